// Round 1
// 1004.873 us; speedup vs baseline: 1.1673x; 1.1673x over previous
//
#include <hip/hip_runtime.h>

// out[b,o,i] = sum_c x[b,c,i] * W[i,o,c] + bias[i,o]
//   x:   [64, 256, 2048] fp32
//   W:   [2048, 256, 256] fp32   (o-major, c contiguous -> perfect B^T MFMA feed)
//   bias:[2048, 256] fp32
//   out: [64, 256, 2048] fp32
//
// Memory-bound: ~807 MB/dispatch ideal, floor ~128 us @ 6.3 TB/s.
// Each WG: 2 consecutive positions, full M=64, N=256, K=256.
// W streamed global->reg with inline fp32->bf16 (RNE); x staged in LDS as bf16.
//
// R1 change: bijective XCD swizzle so each XCD owns 256 contiguous positions.
//   The 8 WGs sharing each 64B out-line (and each 64B x-line) now run on the
//   SAME XCD's L2 -> partial 8B writes merge to full-line evictions, x lines
//   fetched once. W loads marked nontemporal (537MB stream, zero reuse) to
//   keep L2 for the x/out lines that need merging.

constexpr int NPOS = 2048;
constexpr int CIN  = 256;
constexpr int COUT = 256;
constexpr int NB   = 64;   // batch
constexpr int PP   = 2;    // positions per workgroup
constexpr int XS_STRIDE = 264;  // CIN + 8 pad: lane stride 528B -> 2-way bank alias (free)
constexpr int NWG  = NPOS / PP; // 1024
constexpr int NXCD = 8;
constexpr int CPX  = NWG / NXCD; // 128 WGs per XCD (1024 % 8 == 0 -> bijective)

typedef short short8 __attribute__((ext_vector_type(8)));
typedef float f32x4  __attribute__((ext_vector_type(4)));

__device__ __forceinline__ unsigned short f2bf(float f) {
  // round-to-nearest-even fp32 -> bf16 (inputs are finite; no NaN handling needed)
  unsigned int u = __builtin_bit_cast(unsigned int, f);
  u += 0x7FFFu + ((u >> 16) & 1u);
  return (unsigned short)(u >> 16);
}

__global__ __launch_bounds__(256, 2)
void fc_kernel(const float* __restrict__ X, const float* __restrict__ W,
               const float* __restrict__ Bv, float* __restrict__ Out) {
  __shared__ __align__(16) unsigned short xs[PP * NB * XS_STRIDE];
  const int tid = threadIdx.x;

  // ---- XCD-aware swizzle: HW round-robins blockIdx across 8 XCDs; remap so
  // XCD k gets logical blocks [k*CPX, (k+1)*CPX) = 256 contiguous positions.
  const int bid = blockIdx.x;
  const int lb  = (bid & (NXCD - 1)) * CPX + (bid >> 3);
  const int i0  = lb * PP;

  // ---- stage x[b, c, i0:i0+2] -> xs[p][b][c] as bf16 ----
  {
    const int c = tid;  // 0..255 == CIN
    #pragma unroll 4
    for (int b = 0; b < NB; ++b) {
      const float2 v = *(const float2*)(X + ((b * CIN + c) * NPOS + i0));
      xs[(0 * NB + b) * XS_STRIDE + c] = f2bf(v.x);
      xs[(1 * NB + b) * XS_STRIDE + c] = f2bf(v.y);
    }
  }
  __syncthreads();

  const int lane = tid & 63;
  const int wave = tid >> 6;
  const int lr = lane & 15;   // row-within-16
  const int q  = lane >> 4;   // quad
  const int n0 = wave * 64;   // this wave's c_out base (4 waves x 64 couts)

  f32x4 acc[PP][4][4] = {};   // [pos][m-tile][n-tile], 128 VGPRs

  const float* W0 = W + (size_t)(i0 + 0) * (COUT * CIN);
  const float* W1 = W + (size_t)(i0 + 1) * (COUT * CIN);

  for (int k0 = 0; k0 < CIN; k0 += 32) {
    const int kk = k0 + q * 8;

    // A-fragments: A[m=lr][k=q*8+j] -> xs[p][tm*16+lr][kk..kk+7]
    short8 a[PP][4];
    #pragma unroll
    for (int p = 0; p < PP; ++p)
      #pragma unroll
      for (int tm = 0; tm < 4; ++tm)
        a[p][tm] = *(const short8*)&xs[(p * NB + tm * 16 + lr) * XS_STRIDE + kk];

    #pragma unroll
    for (int p = 0; p < PP; ++p) {
      const float* Wi = (p == 0) ? W0 : W1;
      #pragma unroll
      for (int tn = 0; tn < 4; ++tn) {
        // B-fragment: B[n=lr][k=q*8+j] -> W[i][n0+tn*16+lr][kk..kk+7] (32B contiguous/lane)
        const float* wp = Wi + (n0 + tn * 16 + lr) * CIN + kk;
        const f32x4 w0 = __builtin_nontemporal_load((const f32x4*)wp);
        const f32x4 w1 = __builtin_nontemporal_load((const f32x4*)(wp + 4));
        short8 bb;
        bb[0] = (short)f2bf(w0[0]); bb[1] = (short)f2bf(w0[1]);
        bb[2] = (short)f2bf(w0[2]); bb[3] = (short)f2bf(w0[3]);
        bb[4] = (short)f2bf(w1[0]); bb[5] = (short)f2bf(w1[1]);
        bb[6] = (short)f2bf(w1[2]); bb[7] = (short)f2bf(w1[3]);
        #pragma unroll
        for (int tm = 0; tm < 4; ++tm)
          acc[p][tm][tn] = __builtin_amdgcn_mfma_f32_16x16x32_bf16(
              a[p][tm], bb, acc[p][tm][tn], 0, 0, 0);
      }
    }
  }

  // ---- epilogue: + bias, store float2 along contiguous i ----
  // D mapping: row(m=batch) = q*4 + r, col(n=cout) = lr   [measured m89/m91]
  #pragma unroll
  for (int tn = 0; tn < 4; ++tn) {
    const int o = n0 + tn * 16 + lr;
    const float bv0 = Bv[(i0 + 0) * COUT + o];
    const float bv1 = Bv[(i0 + 1) * COUT + o];
    #pragma unroll
    for (int tm = 0; tm < 4; ++tm) {
      #pragma unroll
      for (int r = 0; r < 4; ++r) {
        const int b = tm * 16 + q * 4 + r;
        float2 v;
        v.x = acc[0][tm][tn][r] + bv0;
        v.y = acc[1][tm][tn][r] + bv1;
        *(float2*)(Out + ((b * COUT + o) * NPOS + i0)) = v;
      }
    }
  }
}

extern "C" void kernel_launch(void* const* d_in, const int* in_sizes, int n_in,
                              void* d_out, int out_size, void* d_ws, size_t ws_size,
                              hipStream_t stream) {
  const float* X  = (const float*)d_in[0];
  const float* W  = (const float*)d_in[1];
  const float* Bv = (const float*)d_in[2];
  float* Out = (float*)d_out;
  dim3 grid(NWG);
  dim3 block(256);
  fc_kernel<<<grid, block, 0, stream>>>(X, W, Bv, Out);
}